// Round 5
// baseline (914.218 us; speedup 1.0000x reference)
//
#include <hip/hip_runtime.h>
#include <cstdint>
#include <cstddef>

// ---------------------------------------------------------------------------
// GCN 3-layer forward. bf16 storage + bf16 MFMA gemms, f32 accumulation.
// gemm epilogue pre-scales rows by dinv[row] so aggregation is a pure sum:
//   out[d] = dinv[d] * (sum_{s in N(d)} hs[s] + hs[d]) + bias
// CSR built via 128-node buckets to avoid scatter write amplification.
// ---------------------------------------------------------------------------

typedef unsigned int uint32;
typedef __attribute__((ext_vector_type(8))) short bf16x8;
typedef __attribute__((ext_vector_type(4))) float f32x4;

__device__ inline float bl(uint32 u) { uint32 v = u << 16; return __builtin_bit_cast(float, v); }
__device__ inline float bh(uint32 u) { uint32 v = u & 0xffff0000u; return __builtin_bit_cast(float, v); }
__device__ inline uint32 f2b(float f) {   // RNE f32 -> bf16 bits
    uint32 u = __builtin_bit_cast(uint32, f);
    return (u + 0x7fffu + ((u >> 16) & 1u)) >> 16;
}
__device__ inline uint32 pack2(float x, float y) { return f2b(x) | (f2b(y) << 16); }

#define MFMA16(a, b, c) __builtin_amdgcn_mfma_f32_16x16x32_bf16(a, b, c, 0, 0, 0)

// ---------------- bucketed CSR build ----------------
// bucket b covers nodes [b*128, b*128+128); packed entry = src | (dst&127)<<17

__global__ __launch_bounds__(256) void bucket_hist(const int* __restrict__ dst,
                                                   int* __restrict__ bcnt,
                                                   int E, int NB) {
    __shared__ int lh[1024];
    for (int t = threadIdx.x; t < NB; t += 256) lh[t] = 0;
    __syncthreads();
    int stride = gridDim.x * 256;
    for (int e = blockIdx.x * 256 + threadIdx.x; e < E; e += stride)
        atomicAdd(&lh[dst[e] >> 7], 1);
    __syncthreads();
    for (int t = threadIdx.x; t < NB; t += 256)
        if (lh[t]) atomicAdd(&bcnt[t], lh[t]);
}

__global__ __launch_bounds__(1024) void bucket_scan(const int* __restrict__ bcnt,
                                                    int* __restrict__ boffs,
                                                    int* __restrict__ bcur, int nb) {
    __shared__ int s[1024];
    int tx = threadIdx.x;
    int v = (tx < nb) ? bcnt[tx] : 0;
    s[tx] = v;
    __syncthreads();
    for (int off = 1; off < 1024; off <<= 1) {
        int t = (tx >= off) ? s[tx - off] : 0;
        __syncthreads();
        s[tx] += t;
        __syncthreads();
    }
    if (tx < nb) {
        int ex = s[tx] - v;
        boffs[tx] = ex;
        bcur[tx] = ex;
    }
    if (tx == 0) boffs[nb] = s[1023];
}

__global__ __launch_bounds__(256) void bucket_fill(const int* __restrict__ src,
                                                   const int* __restrict__ dst,
                                                   int* __restrict__ bcur,
                                                   uint32* __restrict__ bkt, int E) {
    int stride = gridDim.x * 256;
    for (int e = blockIdx.x * 256 + threadIdx.x; e < E; e += stride) {
        int d = dst[e];
        int b = d >> 7;
        int pos = atomicAdd(&bcur[b], 1);
        bkt[pos] = (uint32)src[e] | ((uint32)(d & 127) << 17);
    }
}

// per-bucket node degree + dinv (replaces global-atomic count_deg)
__global__ __launch_bounds__(256) void cnt_dinv(const uint32* __restrict__ bkt,
                                                const int* __restrict__ boffs,
                                                int* __restrict__ cnt,
                                                float* __restrict__ dinv, int n) {
    __shared__ int lcnt[128];
    int b = blockIdx.x;
    if (threadIdx.x < 128) lcnt[threadIdx.x] = 0;
    __syncthreads();
    int j0 = boffs[b], j1 = boffs[b + 1];
    for (int j = j0 + threadIdx.x; j < j1; j += 256)
        atomicAdd(&lcnt[bkt[j] >> 17], 1);
    __syncthreads();
    if (threadIdx.x < 128) {
        int node = b * 128 + threadIdx.x;
        if (node < n) {
            int c = lcnt[threadIdx.x];
            cnt[node] = c;
            dinv[node] = rsqrtf((float)(c + 1));  // +1 self loop
        }
    }
}

__global__ __launch_bounds__(256) void scan1(const int* __restrict__ cnt,
                                             int* __restrict__ offs,
                                             int* __restrict__ bsums, int n) {
    __shared__ int s[256];
    int tx = threadIdx.x;
    int i = blockIdx.x * 256 + tx;
    int v = (i < n) ? cnt[i] : 0;
    s[tx] = v;
    __syncthreads();
    for (int off = 1; off < 256; off <<= 1) {
        int t = (tx >= off) ? s[tx - off] : 0;
        __syncthreads();
        s[tx] += t;
        __syncthreads();
    }
    if (i < n) offs[i] = s[tx] - v;
    if (tx == 255) bsums[blockIdx.x] = s[255];
}

__global__ __launch_bounds__(512) void scan2(const int* __restrict__ bsums,
                                             int* __restrict__ bscan, int nb) {
    __shared__ int s[512];
    int tx = threadIdx.x;
    int v = (tx < nb) ? bsums[tx] : 0;
    s[tx] = v;
    __syncthreads();
    for (int off = 1; off < 512; off <<= 1) {
        int t = (tx >= off) ? s[tx - off] : 0;
        __syncthreads();
        s[tx] += t;
        __syncthreads();
    }
    if (tx < nb) bscan[tx] = s[tx] - v;
}

__global__ __launch_bounds__(256) void scan3(int* __restrict__ offs,
                                             const int* __restrict__ bscan,
                                             int n, int E) {
    int i = blockIdx.x * 256 + threadIdx.x;
    if (i < n) offs[i] += bscan[blockIdx.x];
    if (i == 0) offs[n] = E;
}

// per-bucket scatter into the bucket's contiguous CSR span (L2-hot)
__global__ __launch_bounds__(256) void csr_fill2(const uint32* __restrict__ bkt,
                                                 const int* __restrict__ boffs,
                                                 const int* __restrict__ offs,
                                                 int* __restrict__ csr, int n) {
    __shared__ int lcur[128];
    int b = blockIdx.x;
    if (threadIdx.x < 128) {
        int node = b * 128 + threadIdx.x;
        lcur[threadIdx.x] = (node < n) ? offs[node] : 0;
    }
    __syncthreads();
    int j0 = boffs[b], j1 = boffs[b + 1];
    for (int j = j0 + threadIdx.x; j < j1; j += 256) {
        uint32 e = bkt[j];
        int dloc = e >> 17;
        int pos = atomicAdd(&lcur[dloc], 1);
        csr[pos] = (int)(e & 0x1FFFFu);
    }
}

// W (f32 [K][Ncol]) -> WT (bf16 [Nout][128]), Ncol<=Nout (pad cols with 0)
__global__ __launch_bounds__(256) void wconv(const float* __restrict__ W1,
                                             const float* __restrict__ W2,
                                             const float* __restrict__ W3,
                                             unsigned short* __restrict__ wt1,
                                             unsigned short* __restrict__ wt2,
                                             unsigned short* __restrict__ wt3) {
    int b = blockIdx.x, tx = threadIdx.x;
    if (b < 2) {
        const float* S = b ? W2 : W1;
        unsigned short* D = b ? wt2 : wt1;
        for (int i = tx; i < 128 * 128; i += 256) {
            int k = i >> 7, nn = i & 127;
            D[nn * 128 + k] = (unsigned short)f2b(S[i]);
        }
    } else {
        for (int i = tx; i < 48 * 128; i += 256) {
            int k = i / 48, nn = i - k * 48;
            float v = (nn < 40) ? W3[k * 40 + nn] : 0.f;
            wt3[nn * 128 + k] = (unsigned short)f2b(v);
        }
    }
}

// ---------------- MFMA gemms ----------------
// LDS chunk addressing: element off = r*128 + ((kb ^ (r&7))<<3), kb = 16B block

// C[r][c] (bf16 packed pairs, n x 128) = bnrelu(A[r][:]) @ W * dinv[r]
template <bool ABF16, bool BN>
__global__ __launch_bounds__(256) void gemm128m(const void* __restrict__ Av,
                                                const unsigned short* __restrict__ WT,
                                                uint32* __restrict__ C,
                                                const float* __restrict__ dinv, int n,
                                                const float* __restrict__ scale,
                                                const float* __restrict__ shift) {
    __shared__ unsigned short Wls[128 * 128];
    __shared__ unsigned short Als[128 * 128];
    int tx = threadIdx.x;
    int row0 = blockIdx.x * 128;
    {   // stage W: 2048 uint4 chunks
        const uint4* srcW = (const uint4*)WT;
#pragma unroll
        for (int i = 0; i < 8; i++) {
            int cid = tx + 256 * i;
            int nr = cid >> 4, kb = cid & 15;
            uint4 u = srcW[cid];
            *(uint4*)&Wls[nr * 128 + ((kb ^ (nr & 7)) << 3)] = u;
        }
    }
    int kb = tx & 15;
    if (ABF16) {
        const uint4* src = (const uint4*)Av;
        float4 sA, sB, hA_, hB_;
        if (BN) {
            sA = ((const float4*)scale)[kb * 2];
            sB = ((const float4*)scale)[kb * 2 + 1];
            hA_ = ((const float4*)shift)[kb * 2];
            hB_ = ((const float4*)shift)[kb * 2 + 1];
        }
#pragma unroll
        for (int i = 0; i < 8; i++) {
            int r = (tx >> 4) + 16 * i;
            int gr = row0 + r;
            if (gr >= n) gr = n - 1;
            uint4 u = src[(size_t)gr * 16 + kb];
            if (BN) {
                uint4 o;
                o.x = pack2(fmaxf(0.f, bl(u.x) * sA.x + hA_.x), fmaxf(0.f, bh(u.x) * sA.y + hA_.y));
                o.y = pack2(fmaxf(0.f, bl(u.y) * sA.z + hA_.z), fmaxf(0.f, bh(u.y) * sA.w + hA_.w));
                o.z = pack2(fmaxf(0.f, bl(u.z) * sB.x + hB_.x), fmaxf(0.f, bh(u.z) * sB.y + hB_.y));
                o.w = pack2(fmaxf(0.f, bl(u.w) * sB.z + hB_.z), fmaxf(0.f, bh(u.w) * sB.w + hB_.w));
                u = o;
            }
            *(uint4*)&Als[r * 128 + ((kb ^ (r & 7)) << 3)] = u;
        }
    } else {
        const float4* src = (const float4*)Av;
#pragma unroll
        for (int i = 0; i < 8; i++) {
            int r = (tx >> 4) + 16 * i;
            int gr = row0 + r;
            if (gr >= n) gr = n - 1;
            float4 a = src[(size_t)gr * 32 + kb * 2];
            float4 b = src[(size_t)gr * 32 + kb * 2 + 1];
            uint4 u;
            u.x = pack2(a.x, a.y);
            u.y = pack2(a.z, a.w);
            u.z = pack2(b.x, b.y);
            u.w = pack2(b.z, b.w);
            *(uint4*)&Als[r * 128 + ((kb ^ (r & 7)) << 3)] = u;
        }
    }
    __syncthreads();

    int w = tx >> 6, lane = tx & 63;
    int r0 = w * 32;
    int lrow = lane & 15, lkg = lane >> 4;
    f32x4 acc[2][8];
#pragma unroll
    for (int rt = 0; rt < 2; rt++)
#pragma unroll
        for (int nt = 0; nt < 8; nt++) acc[rt][nt] = (f32x4){0.f, 0.f, 0.f, 0.f};
#pragma unroll
    for (int ks = 0; ks < 4; ks++) {
        int kbl = ks * 4 + lkg;
        int r = r0 + lrow;
        bf16x8 a0 = *(const bf16x8*)&Als[r * 128 + ((kbl ^ (r & 7)) << 3)];
        int r2 = r0 + 16 + lrow;
        bf16x8 a1 = *(const bf16x8*)&Als[r2 * 128 + ((kbl ^ (r2 & 7)) << 3)];
#pragma unroll
        for (int nt = 0; nt < 8; nt++) {
            int nr = nt * 16 + lrow;
            bf16x8 b = *(const bf16x8*)&Wls[nr * 128 + ((kbl ^ (nr & 7)) << 3)];
            acc[0][nt] = MFMA16(a0, b, acc[0][nt]);
            acc[1][nt] = MFMA16(a1, b, acc[1][nt]);
        }
    }
    // epilogue: per-wave LDS bounce (wave's own A slice, 8KB), then packed store
    float* SL = (float*)&Als[w * 4096];
#pragma unroll
    for (int rt = 0; rt < 2; rt++) {
#pragma unroll
        for (int nt = 0; nt < 8; nt++)
#pragma unroll
            for (int j = 0; j < 4; j++)
                SL[(lkg * 4 + j) * 128 + nt * 16 + lrow] = acc[rt][nt][j];
#pragma unroll
        for (int i = 0; i < 8; i++) {
            int rloc = i * 2 + (lane >> 5);
            int gr = row0 + r0 + rt * 16 + rloc;
            int cq = lane & 31;
            if (gr < n) {
                float dv = dinv[gr];
                float4 v = *(float4*)&SL[rloc * 128 + cq * 4];
                uint2 o;
                o.x = pack2(v.x * dv, v.y * dv);
                o.y = pack2(v.z * dv, v.w * dv);
                *(uint2*)&C[(size_t)gr * 64 + cq * 2] = o;
            }
        }
        if (rt == 0) __builtin_amdgcn_s_waitcnt(0);  // drain before SL reuse
    }
}

// C[n x 40] bf16 = bnrelu(A bf16) @ W3 * dinv[r]  (N padded to 48 in WT3)
__global__ __launch_bounds__(256) void gemm40m(const uint32* __restrict__ A,
                                               const unsigned short* __restrict__ WT,
                                               unsigned short* __restrict__ C,
                                               const float* __restrict__ dinv, int n,
                                               const float* __restrict__ scale,
                                               const float* __restrict__ shift) {
    __shared__ unsigned short Wls[48 * 128];
    __shared__ unsigned short Als[128 * 128];
    int tx = threadIdx.x;
    int row0 = blockIdx.x * 128;
    {
        const uint4* srcW = (const uint4*)WT;
#pragma unroll
        for (int i = 0; i < 3; i++) {
            int cid = tx + 256 * i;
            int nr = cid >> 4, kb = cid & 15;
            uint4 u = srcW[cid];
            *(uint4*)&Wls[nr * 128 + ((kb ^ (nr & 7)) << 3)] = u;
        }
    }
    int kb = tx & 15;
    {
        const uint4* src = (const uint4*)A;
        float4 sA = ((const float4*)scale)[kb * 2];
        float4 sB = ((const float4*)scale)[kb * 2 + 1];
        float4 hA_ = ((const float4*)shift)[kb * 2];
        float4 hB_ = ((const float4*)shift)[kb * 2 + 1];
#pragma unroll
        for (int i = 0; i < 8; i++) {
            int r = (tx >> 4) + 16 * i;
            int gr = row0 + r;
            if (gr >= n) gr = n - 1;
            uint4 u = src[(size_t)gr * 16 + kb];
            uint4 o;
            o.x = pack2(fmaxf(0.f, bl(u.x) * sA.x + hA_.x), fmaxf(0.f, bh(u.x) * sA.y + hA_.y));
            o.y = pack2(fmaxf(0.f, bl(u.y) * sA.z + hA_.z), fmaxf(0.f, bh(u.y) * sA.w + hA_.w));
            o.z = pack2(fmaxf(0.f, bl(u.z) * sB.x + hB_.x), fmaxf(0.f, bh(u.z) * sB.y + hB_.y));
            o.w = pack2(fmaxf(0.f, bl(u.w) * sB.z + hB_.z), fmaxf(0.f, bh(u.w) * sB.w + hB_.w));
            *(uint4*)&Als[r * 128 + ((kb ^ (r & 7)) << 3)] = o;
        }
    }
    __syncthreads();

    int w = tx >> 6, lane = tx & 63;
    int r0 = w * 32;
    int lrow = lane & 15, lkg = lane >> 4;
    f32x4 acc[2][3];
#pragma unroll
    for (int rt = 0; rt < 2; rt++)
#pragma unroll
        for (int nt = 0; nt < 3; nt++) acc[rt][nt] = (f32x4){0.f, 0.f, 0.f, 0.f};
#pragma unroll
    for (int ks = 0; ks < 4; ks++) {
        int kbl = ks * 4 + lkg;
        int r = r0 + lrow;
        bf16x8 a0 = *(const bf16x8*)&Als[r * 128 + ((kbl ^ (r & 7)) << 3)];
        int r2 = r0 + 16 + lrow;
        bf16x8 a1 = *(const bf16x8*)&Als[r2 * 128 + ((kbl ^ (r2 & 7)) << 3)];
#pragma unroll
        for (int nt = 0; nt < 3; nt++) {
            int nr = nt * 16 + lrow;
            bf16x8 b = *(const bf16x8*)&Wls[nr * 128 + ((kbl ^ (nr & 7)) << 3)];
            acc[0][nt] = MFMA16(a0, b, acc[0][nt]);
            acc[1][nt] = MFMA16(a1, b, acc[1][nt]);
        }
    }
#pragma unroll
    for (int rt = 0; rt < 2; rt++)
#pragma unroll
        for (int j = 0; j < 4; j++) {
            int gr = row0 + r0 + rt * 16 + lkg * 4 + j;
            if (gr < n) {
                float dv = dinv[gr];
#pragma unroll
                for (int nt = 0; nt < 3; nt++) {
                    int col = nt * 16 + lrow;
                    if (col < 40)
                        C[(size_t)gr * 40 + col] = (unsigned short)f2b(acc[rt][nt][j] * dv);
                }
            }
        }
}

// ---------------- aggregation ----------------

// out[d] = pack( dinv[d] * (sum_{s in N(d)} hs[s] + hs[d]) + bias ), 128 bf16 cols
__global__ __launch_bounds__(256) void agg128(const uint32* __restrict__ h,
                                              const int* __restrict__ csr,
                                              const int* __restrict__ offs,
                                              const float* __restrict__ dinv,
                                              const float* __restrict__ bias,
                                              uint32* __restrict__ out, int n) {
    int wid = (blockIdx.x * 256 + threadIdx.x) >> 6;
    int lane = threadIdx.x & 63;
    if (wid >= n) return;
    uint32 self = h[(size_t)wid * 64 + lane];
    float ax0 = bl(self), ay0 = bh(self);
    float ax1 = 0.f, ay1 = 0.f;
    int e0 = offs[wid], e1 = offs[wid + 1];
    int e = e0;
    while (e < e1) {
        int cnt = e1 - e;
        if (cnt > 64) cnt = 64;
        int sl = (lane < cnt) ? csr[e + lane] : 0;
        int j = 0;
        for (; j + 3 < cnt; j += 4) {
            int s0 = __shfl(sl, j, 64);
            int s1 = __shfl(sl, j + 1, 64);
            int s2 = __shfl(sl, j + 2, 64);
            int s3 = __shfl(sl, j + 3, 64);
            uint32 u0 = h[(size_t)s0 * 64 + lane];
            uint32 u1 = h[(size_t)s1 * 64 + lane];
            uint32 u2 = h[(size_t)s2 * 64 + lane];
            uint32 u3 = h[(size_t)s3 * 64 + lane];
            ax0 += bl(u0); ay0 += bh(u0);
            ax1 += bl(u1); ay1 += bh(u1);
            ax0 += bl(u2); ay0 += bh(u2);
            ax1 += bl(u3); ay1 += bh(u3);
        }
        for (; j < cnt; j++) {
            int s = __shfl(sl, j, 64);
            uint32 u = h[(size_t)s * 64 + lane];
            ax0 += bl(u); ay0 += bh(u);
        }
        e += cnt;
    }
    float ax = ax0 + ax1, ay = ay0 + ay1;
    float di = dinv[wid];
    float2 b = ((const float2*)bias)[lane];
    out[(size_t)wid * 64 + lane] = pack2(ax * di + b.x, ay * di + b.y);
}

// 40-col aggregation + bias + log_softmax.  3 lane-groups x 20 cols; FULLY
// CONVERGENT: uniform trip count, every lane executes every __shfl with a
// clamped source; only the dependent loads are predicated.
__global__ __launch_bounds__(256) void agg40_lsm(const uint32* __restrict__ h,
                                                 const int* __restrict__ csr,
                                                 const int* __restrict__ offs,
                                                 const float* __restrict__ dinv,
                                                 const float* __restrict__ bias,
                                                 float* __restrict__ out, int n) {
    int wid = (blockIdx.x * 256 + threadIdx.x) >> 6;
    int lane = threadIdx.x & 63;
    if (wid >= n) return;
    int grp = lane / 20;              // 0,1,2 work; grp==3 (lanes 60-63) idle
    int c = lane - grp * 20;
    bool work = grp < 3;
    float vx = 0.f, vy = 0.f;
    if (grp == 0) {                   // self term once
        uint32 u = h[(size_t)wid * 20 + c];
        vx = bl(u);
        vy = bh(u);
    }
    int e0 = offs[wid], e1 = offs[wid + 1];
    int e = e0;
    while (e < e1) {                  // wave-uniform
        int cnt = e1 - e;
        if (cnt > 64) cnt = 64;
        int sl = (lane < cnt) ? csr[e + lane] : 0;
        int nIt = (cnt + 5) / 6;      // wave-uniform trip count
        for (int it = 0; it < nIt; it++) {
            int j0 = it * 6 + grp;
            int j1 = j0 + 3;
            int s0 = __shfl(sl, (j0 < cnt) ? j0 : 0, 64);   // convergent
            int s1 = __shfl(sl, (j1 < cnt) ? j1 : 0, 64);   // convergent
            if (work && j0 < cnt) {
                uint32 u = h[(size_t)s0 * 20 + c];
                vx += bl(u); vy += bh(u);
            }
            if (work && j1 < cnt) {
                uint32 u = h[(size_t)s1 * 20 + c];
                vx += bl(u); vy += bh(u);
            }
        }
        e += cnt;
    }
    // combine the 3 groups into lanes 0..19 (sources always active here)
    float t1x = __shfl(vx, (lane + 20) & 63, 64), t2x = __shfl(vx, (lane + 40) & 63, 64);
    float t1y = __shfl(vy, (lane + 20) & 63, 64), t2y = __shfl(vy, (lane + 40) & 63, 64);
    vx += t1x + t2x;
    vy += t1y + t2y;
    float di = dinv[wid];
    float v0 = -1e30f, v1 = -1e30f;
    if (lane < 20) {
        v0 = vx * di + bias[2 * lane];
        v1 = vy * di + bias[2 * lane + 1];
    }
    float m = fmaxf(v0, v1);
    for (int off = 16; off; off >>= 1) m = fmaxf(m, __shfl_xor(m, off, 64));
    float ss = (lane < 20) ? (expf(v0 - m) + expf(v1 - m)) : 0.f;
    for (int off = 16; off; off >>= 1) ss += __shfl_xor(ss, off, 64);
    float lg = logf(ss);
    if (lane < 20) {
        float2 o;
        o.x = v0 - m - lg;
        o.y = v1 - m - lg;
        ((float2*)out)[(size_t)wid * 20 + lane] = o;
    }
}

// ---------------- BN stats ----------------

__global__ __launch_bounds__(256) void stats_k(const uint32* __restrict__ h,
                                               float* __restrict__ psum,
                                               float* __restrict__ psq, int n) {
    int c2 = threadIdx.x & 63;
    int g = threadIdx.x >> 6;
    float s0 = 0.f, s1 = 0.f, q0 = 0.f, q1 = 0.f;
    for (int r = blockIdx.x * 4 + g; r < n; r += gridDim.x * 4) {
        uint32 u = h[(size_t)r * 64 + c2];
        float a = bl(u), b = bh(u);
        s0 += a; s1 += b;
        q0 += a * a; q1 += b * b;
    }
    __shared__ float L[4][256];
    L[0][threadIdx.x] = s0;
    L[1][threadIdx.x] = s1;
    L[2][threadIdx.x] = q0;
    L[3][threadIdx.x] = q1;
    __syncthreads();
    if (threadIdx.x < 64) {
        int c = threadIdx.x;
        float S0 = 0, S1 = 0, Q0 = 0, Q1 = 0;
#pragma unroll
        for (int gg = 0; gg < 4; gg++) {
            S0 += L[0][gg * 64 + c];
            S1 += L[1][gg * 64 + c];
            Q0 += L[2][gg * 64 + c];
            Q1 += L[3][gg * 64 + c];
        }
        psum[blockIdx.x * 128 + 2 * c] = S0;
        psum[blockIdx.x * 128 + 2 * c + 1] = S1;
        psq[blockIdx.x * 128 + 2 * c] = Q0;
        psq[blockIdx.x * 128 + 2 * c + 1] = Q1;
    }
}

__global__ void finalize_stats(const float* __restrict__ psum,
                               const float* __restrict__ psq,
                               const float* __restrict__ g,
                               const float* __restrict__ be,
                               float* __restrict__ scale,
                               float* __restrict__ shift, int nb, float invN) {
    int c = threadIdx.x;  // 128 threads
    float s = 0.f, q = 0.f;
    for (int b = 0; b < nb; b++) {
        s += psum[b * 128 + c];
        q += psq[b * 128 + c];
    }
    float mu = s * invN;
    float var = q * invN - mu * mu;
    float sc = g[c] * rsqrtf(var + 1e-5f);
    scale[c] = sc;
    shift[c] = be[c] - mu * sc;
}

extern "C" void kernel_launch(void* const* d_in, const int* in_sizes, int n_in,
                              void* d_out, int out_size, void* d_ws, size_t ws_size,
                              hipStream_t stream) {
    const float* x   = (const float*)d_in[0];
    const float* W1  = (const float*)d_in[1];
    const float* b1  = (const float*)d_in[2];
    const float* W2  = (const float*)d_in[3];
    const float* b2  = (const float*)d_in[4];
    const float* W3  = (const float*)d_in[5];
    const float* b3  = (const float*)d_in[6];
    const float* g1  = (const float*)d_in[7];
    const float* be1 = (const float*)d_in[8];
    const float* g2  = (const float*)d_in[9];
    const float* be2 = (const float*)d_in[10];
    const int*   ei  = (const int*)d_in[11];

    int n = in_sizes[0] / 128;
    int E = in_sizes[11] / 2;
    const int* src = ei;
    const int* dst = ei + E;
    int NB = (n + 127) >> 7;            // 128-node buckets (<=1024 for n<=131072)

    char* p = (char*)d_ws;
    size_t off = 0;
    auto alloc = [&](size_t bytes) -> void* {
        off = (off + 255) & ~(size_t)255;
        void* r = p + off;
        off += bytes;
        return r;
    };
    uint32* hA    = (uint32*)alloc((size_t)n * 64 * 4);   // n x 128 bf16
    uint32* hB    = (uint32*)alloc((size_t)n * 64 * 4);
    float* dinv   = (float*)alloc((size_t)n * 4);
    int*   cnt    = (int*)alloc((size_t)n * 4);
    int*   offs   = (int*)alloc((size_t)(n + 1) * 4);
    int*   bsums  = (int*)alloc(512 * 4);
    int*   bscan  = (int*)alloc(512 * 4);
    int*   csr    = (int*)alloc((size_t)E * 4);
    float* psum   = (float*)alloc(64 * 128 * 4);
    float* psq    = (float*)alloc(64 * 128 * 4);
    float* scale  = (float*)alloc(128 * 4);
    float* shift  = (float*)alloc(128 * 4);
    unsigned short* wt1 = (unsigned short*)alloc(128 * 128 * 2);
    unsigned short* wt2 = (unsigned short*)alloc(128 * 128 * 2);
    unsigned short* wt3 = (unsigned short*)alloc(48 * 128 * 2);
    int*   bcnt   = (int*)alloc((size_t)NB * 4);
    int*   boffs  = (int*)alloc((size_t)(NB + 1) * 4);
    int*   bcur   = (int*)alloc((size_t)NB * 4);
    // bkt aliases hA: dead before the first gemm writes hA (stream-ordered)
    uint32* bkt   = hA;
    (void)ws_size;

    int nbE = (E + 255) / 256;
    int nbN = (n + 255) / 256;
    int gG = (n + 127) / 128;           // 782 mfma-gemm blocks
    int gAgg = (n * 64 + 255) / 256;
    float invN = 1.0f / (float)n;

    hipMemsetAsync(bcnt, 0, (size_t)NB * 4, stream);

    wconv<<<3, 256, 0, stream>>>(W1, W2, W3, wt1, wt2, wt3);
    bucket_hist<<<256, 256, 0, stream>>>(dst, bcnt, E, NB);
    bucket_scan<<<1, 1024, 0, stream>>>(bcnt, boffs, bcur, NB);
    bucket_fill<<<256, 256, 0, stream>>>(src, dst, bcur, bkt, E);
    cnt_dinv<<<NB, 256, 0, stream>>>(bkt, boffs, cnt, dinv, n);
    scan1<<<nbN, 256, 0, stream>>>(cnt, offs, bsums, n);
    scan2<<<1, 512, 0, stream>>>(bsums, bscan, nbN);
    scan3<<<nbN, 256, 0, stream>>>(offs, bscan, n, E);
    csr_fill2<<<NB, 256, 0, stream>>>(bkt, boffs, offs, csr, n);

    // layer 1
    gemm128m<false, false><<<gG, 256, 0, stream>>>(x, wt1, hA, dinv, n, nullptr, nullptr);
    agg128<<<gAgg, 256, 0, stream>>>(hA, csr, offs, dinv, b1, hB, n);
    stats_k<<<64, 256, 0, stream>>>(hB, psum, psq, n);
    finalize_stats<<<1, 128, 0, stream>>>(psum, psq, g1, be1, scale, shift, 64, invN);

    // layer 2
    gemm128m<true, true><<<gG, 256, 0, stream>>>(hB, wt2, hA, dinv, n, scale, shift);
    agg128<<<gAgg, 256, 0, stream>>>(hA, csr, offs, dinv, b2, hB, n);
    stats_k<<<64, 256, 0, stream>>>(hB, psum, psq, n);
    finalize_stats<<<1, 128, 0, stream>>>(psum, psq, g2, be2, scale, shift, 64, invN);

    // layer 3 + log_softmax
    gemm40m<<<gG, 256, 0, stream>>>(hB, wt3, (unsigned short*)hA, dinv, n, scale, shift);
    agg40_lsm<<<gAgg, 256, 0, stream>>>(hA, csr, offs, dinv, b3, (float*)d_out, n);
}

// Round 6
// 578.266 us; speedup vs baseline: 1.5810x; 1.5810x over previous
//
#include <hip/hip_runtime.h>
#include <cstdint>
#include <cstddef>

// ---------------------------------------------------------------------------
// GCN 3-layer forward. bf16 storage + bf16 MFMA gemms, f32 accumulation.
// gemm epilogue pre-scales rows by dinv[row] so aggregation is a pure sum:
//   out[d] = dinv[d] * (sum_{s in N(d)} hs[s] + hs[d]) + bias
// CSR built via 128-node buckets; reservation is per-block (LDS histogram +
// one padded global atomic per (block,bucket)) to avoid atomic contention.
// ---------------------------------------------------------------------------

typedef unsigned int uint32;
typedef __attribute__((ext_vector_type(8))) short bf16x8;
typedef __attribute__((ext_vector_type(4))) float f32x4;

__device__ inline float bl(uint32 u) { uint32 v = u << 16; return __builtin_bit_cast(float, v); }
__device__ inline float bh(uint32 u) { uint32 v = u & 0xffff0000u; return __builtin_bit_cast(float, v); }
__device__ inline uint32 f2b(float f) {   // RNE f32 -> bf16 bits
    uint32 u = __builtin_bit_cast(uint32, f);
    return (u + 0x7fffu + ((u >> 16) & 1u)) >> 16;
}
__device__ inline uint32 pack2(float x, float y) { return f2b(x) | (f2b(y) << 16); }

#define MFMA16(a, b, c) __builtin_amdgcn_mfma_f32_16x16x32_bf16(a, b, c, 0, 0, 0)
#define CSR_CH 4096

// ---------------- bucketed CSR build ----------------
// bucket b covers nodes [b*128, b*128+128); packed entry = src | (dst&127)<<17
// bcnt/bcur are padded: counter i lives at [i*16] (one per 64B line).

__global__ __launch_bounds__(256) void bucket_hist(const int* __restrict__ dst,
                                                   int* __restrict__ bcntp,
                                                   int E, int NB) {
    __shared__ int lh[1024];
    for (int t = threadIdx.x; t < NB; t += 256) lh[t] = 0;
    __syncthreads();
    int stride = gridDim.x * 256;
    for (int e = blockIdx.x * 256 + threadIdx.x; e < E; e += stride)
        atomicAdd(&lh[dst[e] >> 7], 1);
    __syncthreads();
    for (int t = threadIdx.x; t < NB; t += 256)
        if (lh[t]) atomicAdd(&bcntp[t * 16], lh[t]);
}

__global__ __launch_bounds__(1024) void bucket_scan(const int* __restrict__ bcntp,
                                                    int* __restrict__ boffs,
                                                    int* __restrict__ bcurp, int nb) {
    __shared__ int s[1024];
    int tx = threadIdx.x;
    int v = (tx < nb) ? bcntp[tx * 16] : 0;
    s[tx] = v;
    __syncthreads();
    for (int off = 1; off < 1024; off <<= 1) {
        int t = (tx >= off) ? s[tx - off] : 0;
        __syncthreads();
        s[tx] += t;
        __syncthreads();
    }
    if (tx < nb) {
        int ex = s[tx] - v;
        boffs[tx] = ex;
        bcurp[tx * 16] = ex;
    }
    if (tx == 0) boffs[nb] = s[1023];
}

// per-block chunk: LDS hist -> one global atomic per touched bucket -> scatter
__global__ __launch_bounds__(256) void bucket_fill2(const int* __restrict__ src,
                                                    const int* __restrict__ dst,
                                                    int* __restrict__ bcurp,
                                                    uint32* __restrict__ bkt,
                                                    int E, int NB) {
    __shared__ int lh[1024];
    __shared__ int lcur[1024];
    int e0 = blockIdx.x * CSR_CH;
    int e1 = e0 + CSR_CH;
    if (e1 > E) e1 = E;
    for (int t = threadIdx.x; t < NB; t += 256) lh[t] = 0;
    __syncthreads();
    for (int e = e0 + threadIdx.x; e < e1; e += 256)
        atomicAdd(&lh[dst[e] >> 7], 1);
    __syncthreads();
    for (int t = threadIdx.x; t < NB; t += 256)
        lcur[t] = lh[t] ? atomicAdd(&bcurp[t * 16], lh[t]) : 0;
    __syncthreads();
    for (int e = e0 + threadIdx.x; e < e1; e += 256) {
        int d = dst[e];
        int b = d >> 7;
        int pos = atomicAdd(&lcur[b], 1);
        bkt[pos] = (uint32)src[e] | ((uint32)(d & 127) << 17);
    }
}

// per-bucket node degree + dinv
__global__ __launch_bounds__(256) void cnt_dinv(const uint32* __restrict__ bkt,
                                                const int* __restrict__ boffs,
                                                int* __restrict__ cnt,
                                                float* __restrict__ dinv, int n) {
    __shared__ int lcnt[128];
    int b = blockIdx.x;
    if (threadIdx.x < 128) lcnt[threadIdx.x] = 0;
    __syncthreads();
    int j0 = boffs[b], j1 = boffs[b + 1];
    for (int j = j0 + threadIdx.x; j < j1; j += 256)
        atomicAdd(&lcnt[bkt[j] >> 17], 1);
    __syncthreads();
    if (threadIdx.x < 128) {
        int node = b * 128 + threadIdx.x;
        if (node < n) {
            int c = lcnt[threadIdx.x];
            cnt[node] = c;
            dinv[node] = rsqrtf((float)(c + 1));  // +1 self loop
        }
    }
}

__global__ __launch_bounds__(256) void scan1(const int* __restrict__ cnt,
                                             int* __restrict__ offs,
                                             int* __restrict__ bsums, int n) {
    __shared__ int s[256];
    int tx = threadIdx.x;
    int i = blockIdx.x * 256 + tx;
    int v = (i < n) ? cnt[i] : 0;
    s[tx] = v;
    __syncthreads();
    for (int off = 1; off < 256; off <<= 1) {
        int t = (tx >= off) ? s[tx - off] : 0;
        __syncthreads();
        s[tx] += t;
        __syncthreads();
    }
    if (i < n) offs[i] = s[tx] - v;
    if (tx == 255) bsums[blockIdx.x] = s[255];
}

__global__ __launch_bounds__(512) void scan2(const int* __restrict__ bsums,
                                             int* __restrict__ bscan, int nb) {
    __shared__ int s[512];
    int tx = threadIdx.x;
    int v = (tx < nb) ? bsums[tx] : 0;
    s[tx] = v;
    __syncthreads();
    for (int off = 1; off < 512; off <<= 1) {
        int t = (tx >= off) ? s[tx - off] : 0;
        __syncthreads();
        s[tx] += t;
        __syncthreads();
    }
    if (tx < nb) bscan[tx] = s[tx] - v;
}

__global__ __launch_bounds__(256) void scan3(int* __restrict__ offs,
                                             const int* __restrict__ bscan,
                                             int n, int E) {
    int i = blockIdx.x * 256 + threadIdx.x;
    if (i < n) offs[i] += bscan[blockIdx.x];
    if (i == 0) offs[n] = E;
}

// per-bucket scatter into the bucket's contiguous CSR span (L2-hot)
__global__ __launch_bounds__(256) void csr_fill2(const uint32* __restrict__ bkt,
                                                 const int* __restrict__ boffs,
                                                 const int* __restrict__ offs,
                                                 int* __restrict__ csr, int n) {
    __shared__ int lcur[128];
    int b = blockIdx.x;
    if (threadIdx.x < 128) {
        int node = b * 128 + threadIdx.x;
        lcur[threadIdx.x] = (node < n) ? offs[node] : 0;
    }
    __syncthreads();
    int j0 = boffs[b], j1 = boffs[b + 1];
    for (int j = j0 + threadIdx.x; j < j1; j += 256) {
        uint32 e = bkt[j];
        int dloc = e >> 17;
        int pos = atomicAdd(&lcur[dloc], 1);
        csr[pos] = (int)(e & 0x1FFFFu);
    }
}

// W (f32 [K][Ncol]) -> WT (bf16 [Nout][128]), Ncol<=Nout (pad cols with 0)
__global__ __launch_bounds__(256) void wconv(const float* __restrict__ W1,
                                             const float* __restrict__ W2,
                                             const float* __restrict__ W3,
                                             unsigned short* __restrict__ wt1,
                                             unsigned short* __restrict__ wt2,
                                             unsigned short* __restrict__ wt3) {
    int b = blockIdx.x, tx = threadIdx.x;
    if (b < 2) {
        const float* S = b ? W2 : W1;
        unsigned short* D = b ? wt2 : wt1;
        for (int i = tx; i < 128 * 128; i += 256) {
            int k = i >> 7, nn = i & 127;
            D[nn * 128 + k] = (unsigned short)f2b(S[i]);
        }
    } else {
        for (int i = tx; i < 48 * 128; i += 256) {
            int k = i / 48, nn = i - k * 48;
            float v = (nn < 40) ? W3[k * 40 + nn] : 0.f;
            wt3[nn * 128 + k] = (unsigned short)f2b(v);
        }
    }
}

// ---------------- MFMA gemms ----------------
// LDS chunk addressing: element off = r*128 + ((kb ^ (r&7))<<3), kb = 16B block

// C[r][c] (bf16 packed pairs, n x 128) = bnrelu(A[r][:]) @ W * dinv[r]
template <bool ABF16, bool BN>
__global__ __launch_bounds__(256) void gemm128m(const void* __restrict__ Av,
                                                const unsigned short* __restrict__ WT,
                                                uint32* __restrict__ C,
                                                const float* __restrict__ dinv, int n,
                                                const float* __restrict__ scale,
                                                const float* __restrict__ shift) {
    __shared__ unsigned short Wls[128 * 128];
    __shared__ unsigned short Als[128 * 128];
    int tx = threadIdx.x;
    int row0 = blockIdx.x * 128;
    {   // stage W: 2048 uint4 chunks
        const uint4* srcW = (const uint4*)WT;
#pragma unroll
        for (int i = 0; i < 8; i++) {
            int cid = tx + 256 * i;
            int nr = cid >> 4, kb = cid & 15;
            uint4 u = srcW[cid];
            *(uint4*)&Wls[nr * 128 + ((kb ^ (nr & 7)) << 3)] = u;
        }
    }
    int kb = tx & 15;
    if (ABF16) {
        const uint4* src = (const uint4*)Av;
        float4 sA, sB, hA_, hB_;
        if (BN) {
            sA = ((const float4*)scale)[kb * 2];
            sB = ((const float4*)scale)[kb * 2 + 1];
            hA_ = ((const float4*)shift)[kb * 2];
            hB_ = ((const float4*)shift)[kb * 2 + 1];
        }
#pragma unroll
        for (int i = 0; i < 8; i++) {
            int r = (tx >> 4) + 16 * i;
            int gr = row0 + r;
            if (gr >= n) gr = n - 1;
            uint4 u = src[(size_t)gr * 16 + kb];
            if (BN) {
                uint4 o;
                o.x = pack2(fmaxf(0.f, bl(u.x) * sA.x + hA_.x), fmaxf(0.f, bh(u.x) * sA.y + hA_.y));
                o.y = pack2(fmaxf(0.f, bl(u.y) * sA.z + hA_.z), fmaxf(0.f, bh(u.y) * sA.w + hA_.w));
                o.z = pack2(fmaxf(0.f, bl(u.z) * sB.x + hB_.x), fmaxf(0.f, bh(u.z) * sB.y + hB_.y));
                o.w = pack2(fmaxf(0.f, bl(u.w) * sB.z + hB_.z), fmaxf(0.f, bh(u.w) * sB.w + hB_.w));
                u = o;
            }
            *(uint4*)&Als[r * 128 + ((kb ^ (r & 7)) << 3)] = u;
        }
    } else {
        const float4* src = (const float4*)Av;
#pragma unroll
        for (int i = 0; i < 8; i++) {
            int r = (tx >> 4) + 16 * i;
            int gr = row0 + r;
            if (gr >= n) gr = n - 1;
            float4 a = src[(size_t)gr * 32 + kb * 2];
            float4 b = src[(size_t)gr * 32 + kb * 2 + 1];
            uint4 u;
            u.x = pack2(a.x, a.y);
            u.y = pack2(a.z, a.w);
            u.z = pack2(b.x, b.y);
            u.w = pack2(b.z, b.w);
            *(uint4*)&Als[r * 128 + ((kb ^ (r & 7)) << 3)] = u;
        }
    }
    __syncthreads();

    int w = tx >> 6, lane = tx & 63;
    int r0 = w * 32;
    int lrow = lane & 15, lkg = lane >> 4;
    f32x4 acc[2][8];
#pragma unroll
    for (int rt = 0; rt < 2; rt++)
#pragma unroll
        for (int nt = 0; nt < 8; nt++) acc[rt][nt] = (f32x4){0.f, 0.f, 0.f, 0.f};
#pragma unroll
    for (int ks = 0; ks < 4; ks++) {
        int kbl = ks * 4 + lkg;
        int r = r0 + lrow;
        bf16x8 a0 = *(const bf16x8*)&Als[r * 128 + ((kbl ^ (r & 7)) << 3)];
        int r2 = r0 + 16 + lrow;
        bf16x8 a1 = *(const bf16x8*)&Als[r2 * 128 + ((kbl ^ (r2 & 7)) << 3)];
#pragma unroll
        for (int nt = 0; nt < 8; nt++) {
            int nr = nt * 16 + lrow;
            bf16x8 b = *(const bf16x8*)&Wls[nr * 128 + ((kbl ^ (nr & 7)) << 3)];
            acc[0][nt] = MFMA16(a0, b, acc[0][nt]);
            acc[1][nt] = MFMA16(a1, b, acc[1][nt]);
        }
    }
    // epilogue: per-wave LDS bounce (wave's own A slice, 8KB), then packed store
    float* SL = (float*)&Als[w * 4096];
#pragma unroll
    for (int rt = 0; rt < 2; rt++) {
#pragma unroll
        for (int nt = 0; nt < 8; nt++)
#pragma unroll
            for (int j = 0; j < 4; j++)
                SL[(lkg * 4 + j) * 128 + nt * 16 + lrow] = acc[rt][nt][j];
#pragma unroll
        for (int i = 0; i < 8; i++) {
            int rloc = i * 2 + (lane >> 5);
            int gr = row0 + r0 + rt * 16 + rloc;
            int cq = lane & 31;
            if (gr < n) {
                float dv = dinv[gr];
                float4 v = *(float4*)&SL[rloc * 128 + cq * 4];
                uint2 o;
                o.x = pack2(v.x * dv, v.y * dv);
                o.y = pack2(v.z * dv, v.w * dv);
                *(uint2*)&C[(size_t)gr * 64 + cq * 2] = o;
            }
        }
        if (rt == 0) __builtin_amdgcn_s_waitcnt(0);  // drain before SL reuse
    }
}

// C[n x 40] bf16 = bnrelu(A bf16) @ W3 * dinv[r]  (N padded to 48 in WT3)
__global__ __launch_bounds__(256) void gemm40m(const uint32* __restrict__ A,
                                               const unsigned short* __restrict__ WT,
                                               unsigned short* __restrict__ C,
                                               const float* __restrict__ dinv, int n,
                                               const float* __restrict__ scale,
                                               const float* __restrict__ shift) {
    __shared__ unsigned short Wls[48 * 128];
    __shared__ unsigned short Als[128 * 128];
    int tx = threadIdx.x;
    int row0 = blockIdx.x * 128;
    {
        const uint4* srcW = (const uint4*)WT;
#pragma unroll
        for (int i = 0; i < 3; i++) {
            int cid = tx + 256 * i;
            int nr = cid >> 4, kb = cid & 15;
            uint4 u = srcW[cid];
            *(uint4*)&Wls[nr * 128 + ((kb ^ (nr & 7)) << 3)] = u;
        }
    }
    int kb = tx & 15;
    {
        const uint4* src = (const uint4*)A;
        float4 sA = ((const float4*)scale)[kb * 2];
        float4 sB = ((const float4*)scale)[kb * 2 + 1];
        float4 hA_ = ((const float4*)shift)[kb * 2];
        float4 hB_ = ((const float4*)shift)[kb * 2 + 1];
#pragma unroll
        for (int i = 0; i < 8; i++) {
            int r = (tx >> 4) + 16 * i;
            int gr = row0 + r;
            if (gr >= n) gr = n - 1;
            uint4 u = src[(size_t)gr * 16 + kb];
            uint4 o;
            o.x = pack2(fmaxf(0.f, bl(u.x) * sA.x + hA_.x), fmaxf(0.f, bh(u.x) * sA.y + hA_.y));
            o.y = pack2(fmaxf(0.f, bl(u.y) * sA.z + hA_.z), fmaxf(0.f, bh(u.y) * sA.w + hA_.w));
            o.z = pack2(fmaxf(0.f, bl(u.z) * sB.x + hB_.x), fmaxf(0.f, bh(u.z) * sB.y + hB_.y));
            o.w = pack2(fmaxf(0.f, bl(u.w) * sB.z + hB_.z), fmaxf(0.f, bh(u.w) * sB.w + hB_.w));
            *(uint4*)&Als[r * 128 + ((kb ^ (r & 7)) << 3)] = o;
        }
    }
    __syncthreads();

    int w = tx >> 6, lane = tx & 63;
    int r0 = w * 32;
    int lrow = lane & 15, lkg = lane >> 4;
    f32x4 acc[2][3];
#pragma unroll
    for (int rt = 0; rt < 2; rt++)
#pragma unroll
        for (int nt = 0; nt < 3; nt++) acc[rt][nt] = (f32x4){0.f, 0.f, 0.f, 0.f};
#pragma unroll
    for (int ks = 0; ks < 4; ks++) {
        int kbl = ks * 4 + lkg;
        int r = r0 + lrow;
        bf16x8 a0 = *(const bf16x8*)&Als[r * 128 + ((kbl ^ (r & 7)) << 3)];
        int r2 = r0 + 16 + lrow;
        bf16x8 a1 = *(const bf16x8*)&Als[r2 * 128 + ((kbl ^ (r2 & 7)) << 3)];
#pragma unroll
        for (int nt = 0; nt < 3; nt++) {
            int nr = nt * 16 + lrow;
            bf16x8 b = *(const bf16x8*)&Wls[nr * 128 + ((kbl ^ (nr & 7)) << 3)];
            acc[0][nt] = MFMA16(a0, b, acc[0][nt]);
            acc[1][nt] = MFMA16(a1, b, acc[1][nt]);
        }
    }
#pragma unroll
    for (int rt = 0; rt < 2; rt++)
#pragma unroll
        for (int j = 0; j < 4; j++) {
            int gr = row0 + r0 + rt * 16 + lkg * 4 + j;
            if (gr < n) {
                float dv = dinv[gr];
#pragma unroll
                for (int nt = 0; nt < 3; nt++) {
                    int col = nt * 16 + lrow;
                    if (col < 40)
                        C[(size_t)gr * 40 + col] = (unsigned short)f2b(acc[rt][nt][j] * dv);
                }
            }
        }
}

// ---------------- aggregation ----------------

// out[d] = pack( dinv[d] * (sum_{s in N(d)} hs[s] + hs[d]) + bias ), 128 bf16 cols
__global__ __launch_bounds__(256) void agg128(const uint32* __restrict__ h,
                                              const int* __restrict__ csr,
                                              const int* __restrict__ offs,
                                              const float* __restrict__ dinv,
                                              const float* __restrict__ bias,
                                              uint32* __restrict__ out, int n) {
    int wid = (blockIdx.x * 256 + threadIdx.x) >> 6;
    int lane = threadIdx.x & 63;
    if (wid >= n) return;
    uint32 self = h[(size_t)wid * 64 + lane];
    float ax0 = bl(self), ay0 = bh(self);
    float ax1 = 0.f, ay1 = 0.f;
    int e0 = offs[wid], e1 = offs[wid + 1];
    int e = e0;
    while (e < e1) {
        int cnt = e1 - e;
        if (cnt > 64) cnt = 64;
        int sl = (lane < cnt) ? csr[e + lane] : 0;
        int j = 0;
        for (; j + 3 < cnt; j += 4) {
            int s0 = __shfl(sl, j, 64);
            int s1 = __shfl(sl, j + 1, 64);
            int s2 = __shfl(sl, j + 2, 64);
            int s3 = __shfl(sl, j + 3, 64);
            uint32 u0 = h[(size_t)s0 * 64 + lane];
            uint32 u1 = h[(size_t)s1 * 64 + lane];
            uint32 u2 = h[(size_t)s2 * 64 + lane];
            uint32 u3 = h[(size_t)s3 * 64 + lane];
            ax0 += bl(u0); ay0 += bh(u0);
            ax1 += bl(u1); ay1 += bh(u1);
            ax0 += bl(u2); ay0 += bh(u2);
            ax1 += bl(u3); ay1 += bh(u3);
        }
        for (; j < cnt; j++) {
            int s = __shfl(sl, j, 64);
            uint32 u = h[(size_t)s * 64 + lane];
            ax0 += bl(u); ay0 += bh(u);
        }
        e += cnt;
    }
    float ax = ax0 + ax1, ay = ay0 + ay1;
    float di = dinv[wid];
    float2 b = ((const float2*)bias)[lane];
    out[(size_t)wid * 64 + lane] = pack2(ax * di + b.x, ay * di + b.y);
}

// 40-col aggregation + bias + log_softmax.  3 lane-groups x 20 cols; FULLY
// CONVERGENT: uniform trip count, every lane executes every __shfl with a
// clamped source; only the dependent loads are predicated.
__global__ __launch_bounds__(256) void agg40_lsm(const uint32* __restrict__ h,
                                                 const int* __restrict__ csr,
                                                 const int* __restrict__ offs,
                                                 const float* __restrict__ dinv,
                                                 const float* __restrict__ bias,
                                                 float* __restrict__ out, int n) {
    int wid = (blockIdx.x * 256 + threadIdx.x) >> 6;
    int lane = threadIdx.x & 63;
    if (wid >= n) return;
    int grp = lane / 20;              // 0,1,2 work; grp==3 (lanes 60-63) idle
    int c = lane - grp * 20;
    bool work = grp < 3;
    float vx = 0.f, vy = 0.f;
    if (grp == 0) {                   // self term once
        uint32 u = h[(size_t)wid * 20 + c];
        vx = bl(u);
        vy = bh(u);
    }
    int e0 = offs[wid], e1 = offs[wid + 1];
    int e = e0;
    while (e < e1) {                  // wave-uniform
        int cnt = e1 - e;
        if (cnt > 64) cnt = 64;
        int sl = (lane < cnt) ? csr[e + lane] : 0;
        int nIt = (cnt + 5) / 6;      // wave-uniform trip count
        for (int it = 0; it < nIt; it++) {
            int j0 = it * 6 + grp;
            int j1 = j0 + 3;
            int s0 = __shfl(sl, (j0 < cnt) ? j0 : 0, 64);   // convergent
            int s1 = __shfl(sl, (j1 < cnt) ? j1 : 0, 64);   // convergent
            if (work && j0 < cnt) {
                uint32 u = h[(size_t)s0 * 20 + c];
                vx += bl(u); vy += bh(u);
            }
            if (work && j1 < cnt) {
                uint32 u = h[(size_t)s1 * 20 + c];
                vx += bl(u); vy += bh(u);
            }
        }
        e += cnt;
    }
    // combine the 3 groups into lanes 0..19 (sources always active here)
    float t1x = __shfl(vx, (lane + 20) & 63, 64), t2x = __shfl(vx, (lane + 40) & 63, 64);
    float t1y = __shfl(vy, (lane + 20) & 63, 64), t2y = __shfl(vy, (lane + 40) & 63, 64);
    vx += t1x + t2x;
    vy += t1y + t2y;
    float di = dinv[wid];
    float v0 = -1e30f, v1 = -1e30f;
    if (lane < 20) {
        v0 = vx * di + bias[2 * lane];
        v1 = vy * di + bias[2 * lane + 1];
    }
    float m = fmaxf(v0, v1);
    for (int off = 16; off; off >>= 1) m = fmaxf(m, __shfl_xor(m, off, 64));
    float ss = (lane < 20) ? (expf(v0 - m) + expf(v1 - m)) : 0.f;
    for (int off = 16; off; off >>= 1) ss += __shfl_xor(ss, off, 64);
    float lg = logf(ss);
    if (lane < 20) {
        float2 o;
        o.x = v0 - m - lg;
        o.y = v1 - m - lg;
        ((float2*)out)[(size_t)wid * 20 + lane] = o;
    }
}

// ---------------- BN stats ----------------

__global__ __launch_bounds__(256) void stats_k(const uint32* __restrict__ h,
                                               float* __restrict__ psum,
                                               float* __restrict__ psq, int n) {
    int c2 = threadIdx.x & 63;
    int g = threadIdx.x >> 6;
    float s0 = 0.f, s1 = 0.f, q0 = 0.f, q1 = 0.f;
    for (int r = blockIdx.x * 4 + g; r < n; r += gridDim.x * 4) {
        uint32 u = h[(size_t)r * 64 + c2];
        float a = bl(u), b = bh(u);
        s0 += a; s1 += b;
        q0 += a * a; q1 += b * b;
    }
    __shared__ float L[4][256];
    L[0][threadIdx.x] = s0;
    L[1][threadIdx.x] = s1;
    L[2][threadIdx.x] = q0;
    L[3][threadIdx.x] = q1;
    __syncthreads();
    if (threadIdx.x < 64) {
        int c = threadIdx.x;
        float S0 = 0, S1 = 0, Q0 = 0, Q1 = 0;
#pragma unroll
        for (int gg = 0; gg < 4; gg++) {
            S0 += L[0][gg * 64 + c];
            S1 += L[1][gg * 64 + c];
            Q0 += L[2][gg * 64 + c];
            Q1 += L[3][gg * 64 + c];
        }
        psum[blockIdx.x * 128 + 2 * c] = S0;
        psum[blockIdx.x * 128 + 2 * c + 1] = S1;
        psq[blockIdx.x * 128 + 2 * c] = Q0;
        psq[blockIdx.x * 128 + 2 * c + 1] = Q1;
    }
}

__global__ void finalize_stats(const float* __restrict__ psum,
                               const float* __restrict__ psq,
                               const float* __restrict__ g,
                               const float* __restrict__ be,
                               float* __restrict__ scale,
                               float* __restrict__ shift, int nb, float invN) {
    int c = threadIdx.x;  // 128 threads
    float s = 0.f, q = 0.f;
    for (int b = 0; b < nb; b++) {
        s += psum[b * 128 + c];
        q += psq[b * 128 + c];
    }
    float mu = s * invN;
    float var = q * invN - mu * mu;
    float sc = g[c] * rsqrtf(var + 1e-5f);
    scale[c] = sc;
    shift[c] = be[c] - mu * sc;
}

extern "C" void kernel_launch(void* const* d_in, const int* in_sizes, int n_in,
                              void* d_out, int out_size, void* d_ws, size_t ws_size,
                              hipStream_t stream) {
    const float* x   = (const float*)d_in[0];
    const float* W1  = (const float*)d_in[1];
    const float* b1  = (const float*)d_in[2];
    const float* W2  = (const float*)d_in[3];
    const float* b2  = (const float*)d_in[4];
    const float* W3  = (const float*)d_in[5];
    const float* b3  = (const float*)d_in[6];
    const float* g1  = (const float*)d_in[7];
    const float* be1 = (const float*)d_in[8];
    const float* g2  = (const float*)d_in[9];
    const float* be2 = (const float*)d_in[10];
    const int*   ei  = (const int*)d_in[11];

    int n = in_sizes[0] / 128;
    int E = in_sizes[11] / 2;
    const int* src = ei;
    const int* dst = ei + E;
    int NB = (n + 127) >> 7;            // 128-node buckets (<=1024 for n<=131072)

    char* p = (char*)d_ws;
    size_t off = 0;
    auto alloc = [&](size_t bytes) -> void* {
        off = (off + 255) & ~(size_t)255;
        void* r = p + off;
        off += bytes;
        return r;
    };
    uint32* hA    = (uint32*)alloc((size_t)n * 64 * 4);   // n x 128 bf16
    uint32* hB    = (uint32*)alloc((size_t)n * 64 * 4);
    float* dinv   = (float*)alloc((size_t)n * 4);
    int*   cnt    = (int*)alloc((size_t)n * 4);
    int*   offs   = (int*)alloc((size_t)(n + 1) * 4);
    int*   bsums  = (int*)alloc(512 * 4);
    int*   bscan  = (int*)alloc(512 * 4);
    int*   csr    = (int*)alloc((size_t)E * 4);
    float* psum   = (float*)alloc(64 * 128 * 4);
    float* psq    = (float*)alloc(64 * 128 * 4);
    float* scale  = (float*)alloc(128 * 4);
    float* shift  = (float*)alloc(128 * 4);
    unsigned short* wt1 = (unsigned short*)alloc(128 * 128 * 2);
    unsigned short* wt2 = (unsigned short*)alloc(128 * 128 * 2);
    unsigned short* wt3 = (unsigned short*)alloc(48 * 128 * 2);
    int*   bcntp  = (int*)alloc((size_t)NB * 16 * 4);     // padded: 1 counter / 64B
    int*   boffs  = (int*)alloc((size_t)(NB + 1) * 4);
    int*   bcurp  = (int*)alloc((size_t)NB * 16 * 4);     // padded
    // bkt aliases hA: dead before the first gemm writes hA (stream-ordered)
    uint32* bkt   = hA;
    (void)ws_size;

    int nbN = (n + 255) / 256;
    int gG = (n + 127) / 128;           // 782 mfma-gemm blocks
    int gAgg = (n * 64 + 255) / 256;
    int gFill = (E + CSR_CH - 1) / CSR_CH;
    float invN = 1.0f / (float)n;

    hipMemsetAsync(bcntp, 0, (size_t)NB * 16 * 4, stream);

    wconv<<<3, 256, 0, stream>>>(W1, W2, W3, wt1, wt2, wt3);
    bucket_hist<<<256, 256, 0, stream>>>(dst, bcntp, E, NB);
    bucket_scan<<<1, 1024, 0, stream>>>(bcntp, boffs, bcurp, NB);
    bucket_fill2<<<gFill, 256, 0, stream>>>(src, dst, bcurp, bkt, E, NB);
    cnt_dinv<<<NB, 256, 0, stream>>>(bkt, boffs, cnt, dinv, n);
    scan1<<<nbN, 256, 0, stream>>>(cnt, offs, bsums, n);
    scan2<<<1, 512, 0, stream>>>(bsums, bscan, nbN);
    scan3<<<nbN, 256, 0, stream>>>(offs, bscan, n, E);
    csr_fill2<<<NB, 256, 0, stream>>>(bkt, boffs, offs, csr, n);

    // layer 1
    gemm128m<false, false><<<gG, 256, 0, stream>>>(x, wt1, hA, dinv, n, nullptr, nullptr);
    agg128<<<gAgg, 256, 0, stream>>>(hA, csr, offs, dinv, b1, hB, n);
    stats_k<<<64, 256, 0, stream>>>(hB, psum, psq, n);
    finalize_stats<<<1, 128, 0, stream>>>(psum, psq, g1, be1, scale, shift, 64, invN);

    // layer 2
    gemm128m<true, true><<<gG, 256, 0, stream>>>(hB, wt2, hA, dinv, n, scale, shift);
    agg128<<<gAgg, 256, 0, stream>>>(hA, csr, offs, dinv, b2, hB, n);
    stats_k<<<64, 256, 0, stream>>>(hB, psum, psq, n);
    finalize_stats<<<1, 128, 0, stream>>>(psum, psq, g2, be2, scale, shift, 64, invN);

    // layer 3 + log_softmax
    gemm40m<<<gG, 256, 0, stream>>>(hB, wt3, (unsigned short*)hA, dinv, n, scale, shift);
    agg40_lsm<<<gAgg, 256, 0, stream>>>(hA, csr, offs, dinv, b3, (float*)d_out, n);
}

// Round 7
// 426.934 us; speedup vs baseline: 2.1414x; 1.3545x over previous
//
#include <hip/hip_runtime.h>
#include <cstdint>
#include <cstddef>

// ---------------------------------------------------------------------------
// GCN 3-layer forward. bf16 storage + bf16 MFMA gemms, f32 accumulation.
// gemm epilogue pre-scales rows by dinv[row] so aggregation is a pure sum:
//   out[d] = dinv[d] * (sum_{s in N(d)} hs[s] + hs[d]) + bias
// CSR built via 128-node buckets; per-block reservation avoids contention.
// ---------------------------------------------------------------------------

typedef unsigned int uint32;
typedef __attribute__((ext_vector_type(8))) short bf16x8;
typedef __attribute__((ext_vector_type(4))) float f32x4;

__device__ inline float bl(uint32 u) { uint32 v = u << 16; return __builtin_bit_cast(float, v); }
__device__ inline float bh(uint32 u) { uint32 v = u & 0xffff0000u; return __builtin_bit_cast(float, v); }
__device__ inline uint32 f2b(float f) {   // RNE f32 -> bf16 bits
    uint32 u = __builtin_bit_cast(uint32, f);
    return (u + 0x7fffu + ((u >> 16) & 1u)) >> 16;
}
__device__ inline uint32 pack2(float x, float y) { return f2b(x) | (f2b(y) << 16); }

#define MFMA16(a, b, c) __builtin_amdgcn_mfma_f32_16x16x32_bf16(a, b, c, 0, 0, 0)
#define CSR_CH 4096
#define NSTAT 1024

// ---------------- bucketed CSR build ----------------
// bucket b covers nodes [b*128, b*128+128); packed entry = src | (dst&127)<<17
// bcnt/bcur are padded: counter i lives at [i*16] (one per 64B line).

__global__ __launch_bounds__(256) void bucket_hist(const int* __restrict__ dst,
                                                   int* __restrict__ bcntp,
                                                   int E, int NB) {
    __shared__ int lh[1024];
    for (int t = threadIdx.x; t < NB; t += 256) lh[t] = 0;
    __syncthreads();
    int stride = gridDim.x * 256;
    for (int e = blockIdx.x * 256 + threadIdx.x; e < E; e += stride)
        atomicAdd(&lh[dst[e] >> 7], 1);
    __syncthreads();
    for (int t = threadIdx.x; t < NB; t += 256)
        if (lh[t]) atomicAdd(&bcntp[t * 16], lh[t]);
}

__global__ __launch_bounds__(1024) void bucket_scan(const int* __restrict__ bcntp,
                                                    int* __restrict__ boffs,
                                                    int* __restrict__ bcurp, int nb) {
    __shared__ int s[1024];
    int tx = threadIdx.x;
    int v = (tx < nb) ? bcntp[tx * 16] : 0;
    s[tx] = v;
    __syncthreads();
    for (int off = 1; off < 1024; off <<= 1) {
        int t = (tx >= off) ? s[tx - off] : 0;
        __syncthreads();
        s[tx] += t;
        __syncthreads();
    }
    if (tx < nb) {
        int ex = s[tx] - v;
        boffs[tx] = ex;
        bcurp[tx * 16] = ex;
    }
    if (tx == 0) boffs[nb] = s[1023];
}

// per-block chunk: LDS hist -> one global atomic per touched bucket -> scatter
__global__ __launch_bounds__(256) void bucket_fill2(const int* __restrict__ src,
                                                    const int* __restrict__ dst,
                                                    int* __restrict__ bcurp,
                                                    uint32* __restrict__ bkt,
                                                    int E, int NB) {
    __shared__ int lh[1024];
    __shared__ int lcur[1024];
    int e0 = blockIdx.x * CSR_CH;
    int e1 = e0 + CSR_CH;
    if (e1 > E) e1 = E;
    for (int t = threadIdx.x; t < NB; t += 256) lh[t] = 0;
    __syncthreads();
    for (int e = e0 + threadIdx.x; e < e1; e += 256)
        atomicAdd(&lh[dst[e] >> 7], 1);
    __syncthreads();
    for (int t = threadIdx.x; t < NB; t += 256)
        lcur[t] = lh[t] ? atomicAdd(&bcurp[t * 16], lh[t]) : 0;
    __syncthreads();
    for (int e = e0 + threadIdx.x; e < e1; e += 256) {
        int d = dst[e];
        int b = d >> 7;
        int pos = atomicAdd(&lcur[b], 1);
        bkt[pos] = (uint32)src[e] | ((uint32)(d & 127) << 17);
    }
}

// per-bucket node degree + dinv
__global__ __launch_bounds__(256) void cnt_dinv(const uint32* __restrict__ bkt,
                                                const int* __restrict__ boffs,
                                                int* __restrict__ cnt,
                                                float* __restrict__ dinv, int n) {
    __shared__ int lcnt[128];
    int b = blockIdx.x;
    if (threadIdx.x < 128) lcnt[threadIdx.x] = 0;
    __syncthreads();
    int j0 = boffs[b], j1 = boffs[b + 1];
    for (int j = j0 + threadIdx.x; j < j1; j += 256)
        atomicAdd(&lcnt[bkt[j] >> 17], 1);
    __syncthreads();
    if (threadIdx.x < 128) {
        int node = b * 128 + threadIdx.x;
        if (node < n) {
            int c = lcnt[threadIdx.x];
            cnt[node] = c;
            dinv[node] = rsqrtf((float)(c + 1));  // +1 self loop
        }
    }
}

__global__ __launch_bounds__(256) void scan1(const int* __restrict__ cnt,
                                             int* __restrict__ offs,
                                             int* __restrict__ bsums, int n) {
    __shared__ int s[256];
    int tx = threadIdx.x;
    int i = blockIdx.x * 256 + tx;
    int v = (i < n) ? cnt[i] : 0;
    s[tx] = v;
    __syncthreads();
    for (int off = 1; off < 256; off <<= 1) {
        int t = (tx >= off) ? s[tx - off] : 0;
        __syncthreads();
        s[tx] += t;
        __syncthreads();
    }
    if (i < n) offs[i] = s[tx] - v;
    if (tx == 255) bsums[blockIdx.x] = s[255];
}

__global__ __launch_bounds__(512) void scan2(const int* __restrict__ bsums,
                                             int* __restrict__ bscan, int nb) {
    __shared__ int s[512];
    int tx = threadIdx.x;
    int v = (tx < nb) ? bsums[tx] : 0;
    s[tx] = v;
    __syncthreads();
    for (int off = 1; off < 512; off <<= 1) {
        int t = (tx >= off) ? s[tx - off] : 0;
        __syncthreads();
        s[tx] += t;
        __syncthreads();
    }
    if (tx < nb) bscan[tx] = s[tx] - v;
}

__global__ __launch_bounds__(256) void scan3(int* __restrict__ offs,
                                             const int* __restrict__ bscan,
                                             int n, int E) {
    int i = blockIdx.x * 256 + threadIdx.x;
    if (i < n) offs[i] += bscan[blockIdx.x];
    if (i == 0) offs[n] = E;
}

// per-bucket scatter into the bucket's contiguous CSR span (L2-hot)
__global__ __launch_bounds__(256) void csr_fill2(const uint32* __restrict__ bkt,
                                                 const int* __restrict__ boffs,
                                                 const int* __restrict__ offs,
                                                 int* __restrict__ csr, int n) {
    __shared__ int lcur[128];
    int b = blockIdx.x;
    if (threadIdx.x < 128) {
        int node = b * 128 + threadIdx.x;
        lcur[threadIdx.x] = (node < n) ? offs[node] : 0;
    }
    __syncthreads();
    int j0 = boffs[b], j1 = boffs[b + 1];
    for (int j = j0 + threadIdx.x; j < j1; j += 256) {
        uint32 e = bkt[j];
        int dloc = e >> 17;
        int pos = atomicAdd(&lcur[dloc], 1);
        csr[pos] = (int)(e & 0x1FFFFu);
    }
}

// W (f32 [K][Ncol]) -> WT (bf16 [Nout][128]), Ncol<=Nout (pad cols with 0)
__global__ __launch_bounds__(256) void wconv(const float* __restrict__ W1,
                                             const float* __restrict__ W2,
                                             const float* __restrict__ W3,
                                             unsigned short* __restrict__ wt1,
                                             unsigned short* __restrict__ wt2,
                                             unsigned short* __restrict__ wt3) {
    int b = blockIdx.x, tx = threadIdx.x;
    if (b < 2) {
        const float* S = b ? W2 : W1;
        unsigned short* D = b ? wt2 : wt1;
        for (int i = tx; i < 128 * 128; i += 256) {
            int k = i >> 7, nn = i & 127;
            D[nn * 128 + k] = (unsigned short)f2b(S[i]);
        }
    } else {
        for (int i = tx; i < 48 * 128; i += 256) {
            int k = i / 48, nn = i - k * 48;
            float v = (nn < 40) ? W3[k * 40 + nn] : 0.f;
            wt3[nn * 128 + k] = (unsigned short)f2b(v);
        }
    }
}

// ---------------- MFMA gemms ----------------
// LDS chunk addressing: element off = r*128 + ((kb ^ (r&7))<<3), kb = 16B block

// C[r][c] (bf16 packed pairs, n x 128) = bnrelu(A[r][:]) @ W * dinv[r]
template <bool ABF16, bool BN>
__global__ __launch_bounds__(256) void gemm128m(const void* __restrict__ Av,
                                                const unsigned short* __restrict__ WT,
                                                uint32* __restrict__ C,
                                                const float* __restrict__ dinv, int n,
                                                const float* __restrict__ scale,
                                                const float* __restrict__ shift) {
    __shared__ unsigned short Wls[128 * 128];
    __shared__ unsigned short Als[128 * 128];
    int tx = threadIdx.x;
    int row0 = blockIdx.x * 128;
    {   // stage W: 2048 uint4 chunks
        const uint4* srcW = (const uint4*)WT;
#pragma unroll
        for (int i = 0; i < 8; i++) {
            int cid = tx + 256 * i;
            int nr = cid >> 4, kb = cid & 15;
            uint4 u = srcW[cid];
            *(uint4*)&Wls[nr * 128 + ((kb ^ (nr & 7)) << 3)] = u;
        }
    }
    int kb = tx & 15;
    if (ABF16) {
        const uint4* src = (const uint4*)Av;
        float4 sA, sB, hA_, hB_;
        if (BN) {
            sA = ((const float4*)scale)[kb * 2];
            sB = ((const float4*)scale)[kb * 2 + 1];
            hA_ = ((const float4*)shift)[kb * 2];
            hB_ = ((const float4*)shift)[kb * 2 + 1];
        }
#pragma unroll
        for (int i = 0; i < 8; i++) {
            int r = (tx >> 4) + 16 * i;
            int gr = row0 + r;
            if (gr >= n) gr = n - 1;
            uint4 u = src[(size_t)gr * 16 + kb];
            if (BN) {
                uint4 o;
                o.x = pack2(fmaxf(0.f, bl(u.x) * sA.x + hA_.x), fmaxf(0.f, bh(u.x) * sA.y + hA_.y));
                o.y = pack2(fmaxf(0.f, bl(u.y) * sA.z + hA_.z), fmaxf(0.f, bh(u.y) * sA.w + hA_.w));
                o.z = pack2(fmaxf(0.f, bl(u.z) * sB.x + hB_.x), fmaxf(0.f, bh(u.z) * sB.y + hB_.y));
                o.w = pack2(fmaxf(0.f, bl(u.w) * sB.z + hB_.z), fmaxf(0.f, bh(u.w) * sB.w + hB_.w));
                u = o;
            }
            *(uint4*)&Als[r * 128 + ((kb ^ (r & 7)) << 3)] = u;
        }
    } else {
        const float4* src = (const float4*)Av;
#pragma unroll
        for (int i = 0; i < 8; i++) {
            int r = (tx >> 4) + 16 * i;
            int gr = row0 + r;
            if (gr >= n) gr = n - 1;
            float4 a = src[(size_t)gr * 32 + kb * 2];
            float4 b = src[(size_t)gr * 32 + kb * 2 + 1];
            uint4 u;
            u.x = pack2(a.x, a.y);
            u.y = pack2(a.z, a.w);
            u.z = pack2(b.x, b.y);
            u.w = pack2(b.z, b.w);
            *(uint4*)&Als[r * 128 + ((kb ^ (r & 7)) << 3)] = u;
        }
    }
    __syncthreads();

    int w = tx >> 6, lane = tx & 63;
    int r0 = w * 32;
    int lrow = lane & 15, lkg = lane >> 4;
    f32x4 acc[2][8];
#pragma unroll
    for (int rt = 0; rt < 2; rt++)
#pragma unroll
        for (int nt = 0; nt < 8; nt++) acc[rt][nt] = (f32x4){0.f, 0.f, 0.f, 0.f};
#pragma unroll
    for (int ks = 0; ks < 4; ks++) {
        int kbl = ks * 4 + lkg;
        int r = r0 + lrow;
        bf16x8 a0 = *(const bf16x8*)&Als[r * 128 + ((kbl ^ (r & 7)) << 3)];
        int r2 = r0 + 16 + lrow;
        bf16x8 a1 = *(const bf16x8*)&Als[r2 * 128 + ((kbl ^ (r2 & 7)) << 3)];
#pragma unroll
        for (int nt = 0; nt < 8; nt++) {
            int nr = nt * 16 + lrow;
            bf16x8 b = *(const bf16x8*)&Wls[nr * 128 + ((kbl ^ (nr & 7)) << 3)];
            acc[0][nt] = MFMA16(a0, b, acc[0][nt]);
            acc[1][nt] = MFMA16(a1, b, acc[1][nt]);
        }
    }
    // epilogue: per-wave LDS bounce (wave's own A slice, 8KB), then packed store
    float* SL = (float*)&Als[w * 4096];
#pragma unroll
    for (int rt = 0; rt < 2; rt++) {
#pragma unroll
        for (int nt = 0; nt < 8; nt++)
#pragma unroll
            for (int j = 0; j < 4; j++)
                SL[(lkg * 4 + j) * 128 + nt * 16 + lrow] = acc[rt][nt][j];
#pragma unroll
        for (int i = 0; i < 8; i++) {
            int rloc = i * 2 + (lane >> 5);
            int gr = row0 + r0 + rt * 16 + rloc;
            int cq = lane & 31;
            if (gr < n) {
                float dv = dinv[gr];
                float4 v = *(float4*)&SL[rloc * 128 + cq * 4];
                uint2 o;
                o.x = pack2(v.x * dv, v.y * dv);
                o.y = pack2(v.z * dv, v.w * dv);
                *(uint2*)&C[(size_t)gr * 64 + cq * 2] = o;
            }
        }
        if (rt == 0) __builtin_amdgcn_s_waitcnt(0);  // drain before SL reuse
    }
}

// C[n x 40] bf16 = bnrelu(A bf16) @ W3 * dinv[r]  (N padded to 48 in WT3)
__global__ __launch_bounds__(256) void gemm40m(const uint32* __restrict__ A,
                                               const unsigned short* __restrict__ WT,
                                               unsigned short* __restrict__ C,
                                               const float* __restrict__ dinv, int n,
                                               const float* __restrict__ scale,
                                               const float* __restrict__ shift) {
    __shared__ unsigned short Wls[48 * 128];
    __shared__ unsigned short Als[128 * 128];
    int tx = threadIdx.x;
    int row0 = blockIdx.x * 128;
    {
        const uint4* srcW = (const uint4*)WT;
#pragma unroll
        for (int i = 0; i < 3; i++) {
            int cid = tx + 256 * i;
            int nr = cid >> 4, kb = cid & 15;
            uint4 u = srcW[cid];
            *(uint4*)&Wls[nr * 128 + ((kb ^ (nr & 7)) << 3)] = u;
        }
    }
    int kb = tx & 15;
    {
        const uint4* src = (const uint4*)A;
        float4 sA = ((const float4*)scale)[kb * 2];
        float4 sB = ((const float4*)scale)[kb * 2 + 1];
        float4 hA_ = ((const float4*)shift)[kb * 2];
        float4 hB_ = ((const float4*)shift)[kb * 2 + 1];
#pragma unroll
        for (int i = 0; i < 8; i++) {
            int r = (tx >> 4) + 16 * i;
            int gr = row0 + r;
            if (gr >= n) gr = n - 1;
            uint4 u = src[(size_t)gr * 16 + kb];
            uint4 o;
            o.x = pack2(fmaxf(0.f, bl(u.x) * sA.x + hA_.x), fmaxf(0.f, bh(u.x) * sA.y + hA_.y));
            o.y = pack2(fmaxf(0.f, bl(u.y) * sA.z + hA_.z), fmaxf(0.f, bh(u.y) * sA.w + hA_.w));
            o.z = pack2(fmaxf(0.f, bl(u.z) * sB.x + hB_.x), fmaxf(0.f, bh(u.z) * sB.y + hB_.y));
            o.w = pack2(fmaxf(0.f, bl(u.w) * sB.z + hB_.z), fmaxf(0.f, bh(u.w) * sB.w + hB_.w));
            *(uint4*)&Als[r * 128 + ((kb ^ (r & 7)) << 3)] = o;
        }
    }
    __syncthreads();

    int w = tx >> 6, lane = tx & 63;
    int r0 = w * 32;
    int lrow = lane & 15, lkg = lane >> 4;
    f32x4 acc[2][3];
#pragma unroll
    for (int rt = 0; rt < 2; rt++)
#pragma unroll
        for (int nt = 0; nt < 3; nt++) acc[rt][nt] = (f32x4){0.f, 0.f, 0.f, 0.f};
#pragma unroll
    for (int ks = 0; ks < 4; ks++) {
        int kbl = ks * 4 + lkg;
        int r = r0 + lrow;
        bf16x8 a0 = *(const bf16x8*)&Als[r * 128 + ((kbl ^ (r & 7)) << 3)];
        int r2 = r0 + 16 + lrow;
        bf16x8 a1 = *(const bf16x8*)&Als[r2 * 128 + ((kbl ^ (r2 & 7)) << 3)];
#pragma unroll
        for (int nt = 0; nt < 3; nt++) {
            int nr = nt * 16 + lrow;
            bf16x8 b = *(const bf16x8*)&Wls[nr * 128 + ((kbl ^ (nr & 7)) << 3)];
            acc[0][nt] = MFMA16(a0, b, acc[0][nt]);
            acc[1][nt] = MFMA16(a1, b, acc[1][nt]);
        }
    }
#pragma unroll
    for (int rt = 0; rt < 2; rt++)
#pragma unroll
        for (int j = 0; j < 4; j++) {
            int gr = row0 + r0 + rt * 16 + lkg * 4 + j;
            if (gr < n) {
                float dv = dinv[gr];
#pragma unroll
                for (int nt = 0; nt < 3; nt++) {
                    int col = nt * 16 + lrow;
                    if (col < 40)
                        C[(size_t)gr * 40 + col] = (unsigned short)f2b(acc[rt][nt][j] * dv);
                }
            }
        }
}

// ---------------- aggregation ----------------

// out[d] = pack( dinv[d] * (sum_{s in N(d)} hs[s] + hs[d]) + bias ), 128 bf16 cols
__global__ __launch_bounds__(256) void agg128(const uint32* __restrict__ h,
                                              const int* __restrict__ csr,
                                              const int* __restrict__ offs,
                                              const float* __restrict__ dinv,
                                              const float* __restrict__ bias,
                                              uint32* __restrict__ out, int n) {
    int wid = (blockIdx.x * 256 + threadIdx.x) >> 6;
    int lane = threadIdx.x & 63;
    if (wid >= n) return;
    uint32 self = h[(size_t)wid * 64 + lane];
    float ax0 = bl(self), ay0 = bh(self);
    float ax1 = 0.f, ay1 = 0.f;
    int e0 = offs[wid], e1 = offs[wid + 1];
    int e = e0;
    while (e < e1) {
        int cnt = e1 - e;
        if (cnt > 64) cnt = 64;
        int sl = (lane < cnt) ? csr[e + lane] : 0;
        int j = 0;
        for (; j + 3 < cnt; j += 4) {
            int s0 = __shfl(sl, j, 64);
            int s1 = __shfl(sl, j + 1, 64);
            int s2 = __shfl(sl, j + 2, 64);
            int s3 = __shfl(sl, j + 3, 64);
            uint32 u0 = h[(size_t)s0 * 64 + lane];
            uint32 u1 = h[(size_t)s1 * 64 + lane];
            uint32 u2 = h[(size_t)s2 * 64 + lane];
            uint32 u3 = h[(size_t)s3 * 64 + lane];
            ax0 += bl(u0); ay0 += bh(u0);
            ax1 += bl(u1); ay1 += bh(u1);
            ax0 += bl(u2); ay0 += bh(u2);
            ax1 += bl(u3); ay1 += bh(u3);
        }
        for (; j < cnt; j++) {
            int s = __shfl(sl, j, 64);
            uint32 u = h[(size_t)s * 64 + lane];
            ax0 += bl(u); ay0 += bh(u);
        }
        e += cnt;
    }
    float ax = ax0 + ax1, ay = ay0 + ay1;
    float di = dinv[wid];
    float2 b = ((const float2*)bias)[lane];
    out[(size_t)wid * 64 + lane] = pack2(ax * di + b.x, ay * di + b.y);
}

// 40-col aggregation + bias + log_softmax.  3 lane-groups x 20 cols; FULLY
// CONVERGENT: uniform trip count, every lane executes every __shfl with a
// clamped source; only the dependent loads are predicated.
__global__ __launch_bounds__(256) void agg40_lsm(const uint32* __restrict__ h,
                                                 const int* __restrict__ csr,
                                                 const int* __restrict__ offs,
                                                 const float* __restrict__ dinv,
                                                 const float* __restrict__ bias,
                                                 float* __restrict__ out, int n) {
    int wid = (blockIdx.x * 256 + threadIdx.x) >> 6;
    int lane = threadIdx.x & 63;
    if (wid >= n) return;
    int grp = lane / 20;              // 0,1,2 work; grp==3 (lanes 60-63) idle
    int c = lane - grp * 20;
    bool work = grp < 3;
    float vx = 0.f, vy = 0.f;
    if (grp == 0) {                   // self term once
        uint32 u = h[(size_t)wid * 20 + c];
        vx = bl(u);
        vy = bh(u);
    }
    int e0 = offs[wid], e1 = offs[wid + 1];
    int e = e0;
    while (e < e1) {                  // wave-uniform
        int cnt = e1 - e;
        if (cnt > 64) cnt = 64;
        int sl = (lane < cnt) ? csr[e + lane] : 0;
        int nIt = (cnt + 5) / 6;      // wave-uniform trip count
        for (int it = 0; it < nIt; it++) {
            int j0 = it * 6 + grp;
            int j1 = j0 + 3;
            int s0 = __shfl(sl, (j0 < cnt) ? j0 : 0, 64);   // convergent
            int s1 = __shfl(sl, (j1 < cnt) ? j1 : 0, 64);   // convergent
            if (work && j0 < cnt) {
                uint32 u = h[(size_t)s0 * 20 + c];
                vx += bl(u); vy += bh(u);
            }
            if (work && j1 < cnt) {
                uint32 u = h[(size_t)s1 * 20 + c];
                vx += bl(u); vy += bh(u);
            }
        }
        e += cnt;
    }
    // combine the 3 groups into lanes 0..19 (sources always active here)
    float t1x = __shfl(vx, (lane + 20) & 63, 64), t2x = __shfl(vx, (lane + 40) & 63, 64);
    float t1y = __shfl(vy, (lane + 20) & 63, 64), t2y = __shfl(vy, (lane + 40) & 63, 64);
    vx += t1x + t2x;
    vy += t1y + t2y;
    float di = dinv[wid];
    float v0 = -1e30f, v1 = -1e30f;
    if (lane < 20) {
        v0 = vx * di + bias[2 * lane];
        v1 = vy * di + bias[2 * lane + 1];
    }
    float m = fmaxf(v0, v1);
    for (int off = 16; off; off >>= 1) m = fmaxf(m, __shfl_xor(m, off, 64));
    float ss = (lane < 20) ? (expf(v0 - m) + expf(v1 - m)) : 0.f;
    for (int off = 16; off; off >>= 1) ss += __shfl_xor(ss, off, 64);
    float lg = logf(ss);
    if (lane < 20) {
        float2 o;
        o.x = v0 - m - lg;
        o.y = v1 - m - lg;
        ((float2*)out)[(size_t)wid * 20 + lane] = o;
    }
}

// ---------------- BN stats ----------------
// grid NSTAT blocks; each thread reads uint4 (8 bf16 cols); LDS tree reduce.

__global__ __launch_bounds__(256) void stats_k(const uint32* __restrict__ h,
                                               float* __restrict__ psum,
                                               float* __restrict__ psq, int n) {
    int kb = threadIdx.x & 15;     // uint4 index within row (8 cols each)
    int rg = threadIdx.x >> 4;     // 0..15 row group
    float s[8], q[8];
#pragma unroll
    for (int j = 0; j < 8; j++) { s[j] = 0.f; q[j] = 0.f; }
    const uint4* h4 = (const uint4*)h;
    for (int r = blockIdx.x * 16 + rg; r < n; r += gridDim.x * 16) {
        uint4 u = h4[(size_t)r * 16 + kb];
        float f[8] = {bl(u.x), bh(u.x), bl(u.y), bh(u.y),
                      bl(u.z), bh(u.z), bl(u.w), bh(u.w)};
#pragma unroll
        for (int j = 0; j < 8; j++) { s[j] += f[j]; q[j] += f[j] * f[j]; }
    }
    __shared__ float LS[16][16][8];   // [rowgrp][kb][j]  8KB each
    __shared__ float LQ[16][16][8];
#pragma unroll
    for (int j = 0; j < 8; j++) { LS[rg][kb][j] = s[j]; LQ[rg][kb][j] = q[j]; }
    __syncthreads();
    if (threadIdx.x < 128) {
        int cq = threadIdx.x >> 3, j = threadIdx.x & 7;
        float S = 0.f, Q = 0.f;
#pragma unroll
        for (int g = 0; g < 16; g++) { S += LS[g][cq][j]; Q += LQ[g][cq][j]; }
        psum[blockIdx.x * 128 + cq * 8 + j] = S;
        psq[blockIdx.x * 128 + cq * 8 + j] = Q;
    }
}

__global__ __launch_bounds__(1024) void finalize_stats(const float* __restrict__ psum,
                                                       const float* __restrict__ psq,
                                                       const float* __restrict__ g,
                                                       const float* __restrict__ be,
                                                       float* __restrict__ scale,
                                                       float* __restrict__ shift,
                                                       int nb, float invN) {
    int c = threadIdx.x & 127;
    int seg = threadIdx.x >> 7;       // 0..7
    int per = nb >> 3;
    float s = 0.f, q = 0.f;
    for (int b = seg * per; b < (seg + 1) * per; b++) {
        s += psum[b * 128 + c];
        q += psq[b * 128 + c];
    }
    __shared__ float LS[8][128], LQ[8][128];
    LS[seg][c] = s;
    LQ[seg][c] = q;
    __syncthreads();
    if (threadIdx.x < 128) {
        float S = 0.f, Q = 0.f;
#pragma unroll
        for (int g2 = 0; g2 < 8; g2++) { S += LS[g2][c]; Q += LQ[g2][c]; }
        float mu = S * invN;
        float var = Q * invN - mu * mu;
        float sc = g[c] * rsqrtf(var + 1e-5f);
        scale[c] = sc;
        shift[c] = be[c] - mu * sc;
    }
}

extern "C" void kernel_launch(void* const* d_in, const int* in_sizes, int n_in,
                              void* d_out, int out_size, void* d_ws, size_t ws_size,
                              hipStream_t stream) {
    const float* x   = (const float*)d_in[0];
    const float* W1  = (const float*)d_in[1];
    const float* b1  = (const float*)d_in[2];
    const float* W2  = (const float*)d_in[3];
    const float* b2  = (const float*)d_in[4];
    const float* W3  = (const float*)d_in[5];
    const float* b3  = (const float*)d_in[6];
    const float* g1  = (const float*)d_in[7];
    const float* be1 = (const float*)d_in[8];
    const float* g2  = (const float*)d_in[9];
    const float* be2 = (const float*)d_in[10];
    const int*   ei  = (const int*)d_in[11];

    int n = in_sizes[0] / 128;
    int E = in_sizes[11] / 2;
    const int* src = ei;
    const int* dst = ei + E;
    int NB = (n + 127) >> 7;            // 128-node buckets (<=1024 for n<=131072)

    char* p = (char*)d_ws;
    size_t off = 0;
    auto alloc = [&](size_t bytes) -> void* {
        off = (off + 255) & ~(size_t)255;
        void* r = p + off;
        off += bytes;
        return r;
    };
    uint32* hA    = (uint32*)alloc((size_t)n * 64 * 4);   // n x 128 bf16
    uint32* hB    = (uint32*)alloc((size_t)n * 64 * 4);
    float* dinv   = (float*)alloc((size_t)n * 4);
    int*   cnt    = (int*)alloc((size_t)n * 4);
    int*   offs   = (int*)alloc((size_t)(n + 1) * 4);
    int*   bsums  = (int*)alloc(512 * 4);
    int*   bscan  = (int*)alloc(512 * 4);
    int*   csr    = (int*)alloc((size_t)E * 4);
    float* psum   = (float*)alloc((size_t)NSTAT * 128 * 4);
    float* psq    = (float*)alloc((size_t)NSTAT * 128 * 4);
    float* scale  = (float*)alloc(128 * 4);
    float* shift  = (float*)alloc(128 * 4);
    unsigned short* wt1 = (unsigned short*)alloc(128 * 128 * 2);
    unsigned short* wt2 = (unsigned short*)alloc(128 * 128 * 2);
    unsigned short* wt3 = (unsigned short*)alloc(48 * 128 * 2);
    int*   bcntp  = (int*)alloc((size_t)NB * 16 * 4);     // padded: 1 counter / 64B
    int*   boffs  = (int*)alloc((size_t)(NB + 1) * 4);
    int*   bcurp  = (int*)alloc((size_t)NB * 16 * 4);     // padded
    // bkt aliases hA: dead before the first gemm writes hA (stream-ordered)
    uint32* bkt   = hA;
    (void)ws_size;

    int nbN = (n + 255) / 256;
    int gG = (n + 127) / 128;           // 782 mfma-gemm blocks
    int gAgg = (n * 64 + 255) / 256;
    int gFill = (E + CSR_CH - 1) / CSR_CH;
    float invN = 1.0f / (float)n;

    hipMemsetAsync(bcntp, 0, (size_t)NB * 16 * 4, stream);

    wconv<<<3, 256, 0, stream>>>(W1, W2, W3, wt1, wt2, wt3);
    bucket_hist<<<256, 256, 0, stream>>>(dst, bcntp, E, NB);
    bucket_scan<<<1, 1024, 0, stream>>>(bcntp, boffs, bcurp, NB);
    bucket_fill2<<<gFill, 256, 0, stream>>>(src, dst, bcurp, bkt, E, NB);
    cnt_dinv<<<NB, 256, 0, stream>>>(bkt, boffs, cnt, dinv, n);
    scan1<<<nbN, 256, 0, stream>>>(cnt, offs, bsums, n);
    scan2<<<1, 512, 0, stream>>>(bsums, bscan, nbN);
    scan3<<<nbN, 256, 0, stream>>>(offs, bscan, n, E);
    csr_fill2<<<NB, 256, 0, stream>>>(bkt, boffs, offs, csr, n);

    // layer 1
    gemm128m<false, false><<<gG, 256, 0, stream>>>(x, wt1, hA, dinv, n, nullptr, nullptr);
    agg128<<<gAgg, 256, 0, stream>>>(hA, csr, offs, dinv, b1, hB, n);
    stats_k<<<NSTAT, 256, 0, stream>>>(hB, psum, psq, n);
    finalize_stats<<<1, 1024, 0, stream>>>(psum, psq, g1, be1, scale, shift, NSTAT, invN);

    // layer 2
    gemm128m<true, true><<<gG, 256, 0, stream>>>(hB, wt2, hA, dinv, n, scale, shift);
    agg128<<<gAgg, 256, 0, stream>>>(hA, csr, offs, dinv, b2, hB, n);
    stats_k<<<NSTAT, 256, 0, stream>>>(hB, psum, psq, n);
    finalize_stats<<<1, 1024, 0, stream>>>(psum, psq, g2, be2, scale, shift, NSTAT, invN);

    // layer 3 + log_softmax
    gemm40m<<<gG, 256, 0, stream>>>(hB, wt3, (unsigned short*)hA, dinv, n, scale, shift);
    agg40_lsm<<<gAgg, 256, 0, stream>>>(hA, csr, offs, dinv, b3, (float*)d_out, n);
}